// Round 6
// baseline (1221.818 us; speedup 1.0000x reference)
//
#include <hip/hip_runtime.h>
#include <hip/hip_bf16.h>

// EMAVectorQuantizer: B=8, D=256, T=1024, BT=8192, N=16384
// Outputs (FLOAT32, concat): out[B,D,T], perplexity, idx[BT], loss,
// new_weight[N,D], new_cluster_size[N], new_embed_avg[N,D] = 10,510,338 f32

#define B_ 8
#define D_ 256
#define T_ 1024
#define BT_ 8192
#define N_ 16384

// d_out element offsets (float32 elements)
#define O_OUT   0
#define O_PERP  2097152
#define O_IDX   2097153
#define O_LOSS  2105345
#define O_NEWW  2105346
#define O_NCS   6299650
#define O_NEA   6316034

// fixed workspace region (704 KB); es[N][W] follows at W_ES
#define W_CNT   0ull        // counts[N] f32 (zeroed)
#define W_SCAL  65536ull    // scalars: [0]=loss_sum [1]=ent [2]=ntot (zeroed)
#define W_Z2    65792ull    // z2[BT] f32
#define W_W2    98560ull    // w2[N] f32
#define W_IDXI  164096ull   // idx int32[BT]
#define W_PACK  196864ull   // pack[BT][8] u64 per-chunk argmin candidates
#define W_ES    721152ull   // es[N][W] f32 (zeroed per pass); ws_size>=4.92MB proven

// ---------------- z2[b*T+t] = sum_d z[b][d][t]^2 ----------------
__global__ void k_z2_r6(const float* __restrict__ z, float* __restrict__ z2) {
  __shared__ float part[4][64];
  const int blk = blockIdx.x;  // b*16 + tchunk
  const int b = blk >> 4, t0 = (blk & 15) << 6;
  const int lane = threadIdx.x & 63, w = threadIdx.x >> 6;
  const float* base = z + (size_t)b * D_ * T_ + t0 + lane;
  float s = 0.f;
  for (int d = w * 64; d < w * 64 + 64; ++d) {
    const float v = base[(size_t)d * T_];
    s = fmaf(v, v, s);
  }
  part[w][lane] = s;
  __syncthreads();
  if (w == 0)
    z2[b * T_ + t0 + lane] = part[0][lane] + part[1][lane] + part[2][lane] + part[3][lane];
}

// ---------------- w2[n] = ||weight[n]||^2 ----------------
__global__ void k_rowsq_r6(const float* __restrict__ m, float* __restrict__ outv) {
  const int row = blockIdx.x * 4 + (threadIdx.x >> 6);
  const int lane = threadIdx.x & 63;
  const float4 v = reinterpret_cast<const float4*>(m + (size_t)row * D_)[lane];
  float s = v.x * v.x + v.y * v.y + v.z * v.z + v.w * v.w;
  for (int o = 32; o; o >>= 1) s += __shfl_xor(s, o);
  if (lane == 0) outv[row] = s;
}

// ---------------- fp32 distance GEMM + per-chunk argmin candidate ----------
// grid (64 row-blocks of 128, 8 code-chunks of 2048); 256 threads.
__global__ void k_dist_r6(const float* __restrict__ z, const float* __restrict__ weight,
                          const float* __restrict__ z2, const float* __restrict__ w2,
                          unsigned long long* __restrict__ pack) {
  __shared__ float As[32][128];
  __shared__ float Bs[32][128];
  __shared__ float z2s[128];
  __shared__ float w2s[128];

  const int tid = threadIdx.x;
  const int tx = tid & 15, ty = tid >> 4;
  const int rowblk = blockIdx.x;
  const int b = rowblk >> 3, t0 = (rowblk & 7) << 7;
  const int r0 = rowblk << 7;
  const int cy = blockIdx.y;
  const int nbase = cy << 11;

  if (tid < 128) z2s[tid] = z2[r0 + tid];

  float runmin[8];
  int runidx[8];
#pragma unroll
  for (int i = 0; i < 8; ++i) { runmin[i] = 3.0e38f; runidx[i] = 0; }

  const int m4 = tid & 31, kk = tid >> 5;
  const int nn = tid >> 3, kq = tid & 7;
  const float* zbase = z + (size_t)b * D_ * T_ + t0;

  for (int tile = 0; tile < 16; ++tile) {
    const int n0 = nbase + (tile << 7);
    __syncthreads();
    if (tid < 128) w2s[tid] = w2[n0 + tid];
    float acc[8][8];
#pragma unroll
    for (int i = 0; i < 8; ++i)
#pragma unroll
      for (int j = 0; j < 8; ++j) acc[i][j] = 0.f;

    for (int kc = 0; kc < D_; kc += 32) {
      __syncthreads();
#pragma unroll
      for (int p = 0; p < 4; ++p) {
        const int k = kk + (p << 3);
        *reinterpret_cast<float4*>(&As[k][m4 << 2]) =
            *reinterpret_cast<const float4*>(zbase + (size_t)(kc + k) * T_ + (m4 << 2));
      }
#pragma unroll
      for (int p = 0; p < 4; ++p) {
        const int n = nn + (p << 5);
        const float4 v = *reinterpret_cast<const float4*>(weight + (size_t)(n0 + n) * D_ + kc + (kq << 2));
        Bs[(kq << 2) + 0][n] = v.x;
        Bs[(kq << 2) + 1][n] = v.y;
        Bs[(kq << 2) + 2][n] = v.z;
        Bs[(kq << 2) + 3][n] = v.w;
      }
      __syncthreads();
#pragma unroll 8
      for (int k = 0; k < 32; ++k) {
        float av[8], bv[8];
        *reinterpret_cast<float4*>(&av[0]) = *reinterpret_cast<const float4*>(&As[k][ty << 2]);
        *reinterpret_cast<float4*>(&av[4]) = *reinterpret_cast<const float4*>(&As[k][64 + (ty << 2)]);
        *reinterpret_cast<float4*>(&bv[0]) = *reinterpret_cast<const float4*>(&Bs[k][tx << 2]);
        *reinterpret_cast<float4*>(&bv[4]) = *reinterpret_cast<const float4*>(&Bs[k][64 + (tx << 2)]);
#pragma unroll
        for (int i = 0; i < 8; ++i)
#pragma unroll
          for (int j = 0; j < 8; ++j) acc[i][j] = fmaf(av[i], bv[j], acc[i][j]);
      }
    }
#pragma unroll
    for (int i = 0; i < 8; ++i) {
      const int ml = (ty << 2) + (i & 3) + ((i >> 2) << 6);
      const float zz = z2s[ml];
#pragma unroll
      for (int j = 0; j < 8; ++j) {
        const int nl = (tx << 2) + (j & 3) + ((j >> 2) << 6);
        const float dd = zz + w2s[nl] - 2.0f * acc[i][j];
        if (dd < runmin[i]) { runmin[i] = dd; runidx[i] = n0 + nl; }
      }
    }
  }
#pragma unroll
  for (int i = 0; i < 8; ++i) {
    float m = runmin[i];
    int id = runidx[i];
    for (int o = 8; o; o >>= 1) {
      const float om = __shfl_xor(m, o);
      const int oid = __shfl_xor(id, o);
      if (om < m || (om == m && oid < id)) { m = om; id = oid; }
    }
    if (tx == 0) {
      const int ml = (ty << 2) + (i & 3) + ((i >> 2) << 6);
      pack[(size_t)(r0 + ml) * 8 + cy] =
          ((unsigned long long)__float_as_uint(m) << 32) | (unsigned int)id;
    }
  }
}

// ---- fp64 re-rank of the 8 per-chunk candidates; idx + counts + loss -------
// one wave per row; lane holds 4 z coords.
__global__ void k_cand_r6(const float* __restrict__ z, const float* __restrict__ weight,
                          const unsigned long long* __restrict__ pack,
                          int* __restrict__ idxi, float* __restrict__ counts,
                          float* __restrict__ oidx, float* __restrict__ loss_acc) {
  const int row = blockIdx.x * 4 + (threadIdx.x >> 6);
  const int lane = threadIdx.x & 63;
  const int b = row >> 10, t = row & 1023;
  float zc[4];
#pragma unroll
  for (int c = 0; c < 4; ++c)
    zc[c] = z[((size_t)b * D_ + (lane << 2) + c) * T_ + t];
  double best = 1.0e300;
  int bestid = 0;
#pragma unroll
  for (int c = 0; c < 8; ++c) {
    const int cand = (int)(pack[(size_t)row * 8 + c] & 0xFFFFFFFFull) & 16383;
    const float4 wv = reinterpret_cast<const float4*>(weight + (size_t)cand * D_)[lane];
    const double d0 = (double)zc[0] - (double)wv.x;
    const double d1 = (double)zc[1] - (double)wv.y;
    const double d2 = (double)zc[2] - (double)wv.z;
    const double d3 = (double)zc[3] - (double)wv.w;
    double s = d0 * d0 + d1 * d1 + d2 * d2 + d3 * d3;
    for (int o = 32; o; o >>= 1) s += __shfl_xor(s, o);
    // candidates arrive in ascending idx order; strict < keeps lowest idx
    if (s < best) { best = s; bestid = cand; }
  }
  if (lane == 0) {
    idxi[row] = bestid;
    oidx[row] = (float)bestid;
    atomicAdd(&counts[bestid], 1.0f);
    atomicAdd(loss_acc, (float)best);
  }
}

// ---------------- gather codebook rows -> out[B,D,T] (f32) ----------------
__global__ void k_gather_r6(const float* __restrict__ weight, const int* __restrict__ idxi,
                            float* __restrict__ oout) {
  __shared__ float tile[32][257];
  __shared__ int ids[32];
  const int b = blockIdx.y, t0 = blockIdx.x << 5;
  const int lane = threadIdx.x & 63, wave = threadIdx.x >> 6;
  if (threadIdx.x < 32) ids[threadIdx.x] = idxi[b * T_ + t0 + threadIdx.x] & 16383;
  __syncthreads();
  for (int i = 0; i < 8; ++i) {
    const int tl = (wave << 3) + i;
    const float4 v = reinterpret_cast<const float4*>(weight + (size_t)ids[tl] * D_)[lane];
    tile[tl][(lane << 2) + 0] = v.x;
    tile[tl][(lane << 2) + 1] = v.y;
    tile[tl][(lane << 2) + 2] = v.z;
    tile[tl][(lane << 2) + 3] = v.w;
  }
  __syncthreads();
  const int tp = threadIdx.x & 31, dg = threadIdx.x >> 5;
  for (int it = 0; it < 32; ++it) {
    const int d = (dg << 5) + it;
    oout[((size_t)b * D_ + d) * T_ + t0 + tp] = tile[tp][d];
  }
}

// ---------------- embed_sum scatter for d in [dbase, dbase+W), W>=64 --------
__global__ void k_scatter_r6(const float* __restrict__ z, const int* __restrict__ idxi,
                             float* __restrict__ es, int dbase, int W) {
  __shared__ float lds[64][65];
  __shared__ int ids[64];
  const int blk = blockIdx.x;
  const int b = blk >> 4, t0 = (blk & 15) << 6;
  const int lane = threadIdx.x & 63, w = threadIdx.x >> 6;
  if (threadIdx.x < 64) ids[threadIdx.x] = idxi[b * T_ + t0 + threadIdx.x] & 16383;
  for (int dc = 0; dc < W; dc += 64) {
    __syncthreads();
    for (int i = 0; i < 16; ++i) {
      const int ddd = (w << 4) + i;
      lds[ddd][lane] = z[((size_t)b * D_ + dbase + dc + ddd) * T_ + t0 + lane];
    }
    __syncthreads();
    for (int i = 0; i < 16; ++i) {
      const int tl = (w << 4) + i;
      atomicAdd(&es[(size_t)ids[tl] * W + dc + lane], lds[lane][tl]);
    }
  }
}

// ---------------- new_cluster_size (f32) + entropy + ntot ----------------
__global__ void k_fincnt_r6(const float* __restrict__ cs, const float* __restrict__ counts,
                            float* __restrict__ oncs, float* __restrict__ ent_acc,
                            float* __restrict__ ntot_acc) {
  __shared__ float red[8];
  const int n = blockIdx.x * 256 + threadIdx.x;
  const float c = counts[n];
  const float ncs = 0.99f * cs[n] + 0.01f * c;
  oncs[n] = ncs;
  const float p = c * (1.0f / 8192.0f);
  float se = p * logf(p + 1e-10f);
  float sn = ncs;
  for (int o = 32; o; o >>= 1) {
    se += __shfl_xor(se, o);
    sn += __shfl_xor(sn, o);
  }
  const int lane = threadIdx.x & 63, wave = threadIdx.x >> 6;
  if (lane == 0) { red[wave] = se; red[4 + wave] = sn; }
  __syncthreads();
  if (threadIdx.x == 0) {
    atomicAdd(ent_acc, red[0] + red[1] + red[2] + red[3]);
    atomicAdd(ntot_acc, red[4] + red[5] + red[6] + red[7]);
  }
}

// ---------------- new_embed_avg + new_weight (f32) for d-chunk ----------------
__global__ void k_finw_r6(const float* __restrict__ ea, const float* __restrict__ es,
                          const float* __restrict__ cs, const float* __restrict__ counts,
                          const float* __restrict__ ntot_acc, int dbase, int W,
                          float* __restrict__ oneww, float* __restrict__ onea) {
  const int n = blockIdx.x;
  const int dl = threadIdx.x << 1;
  const int d = dbase + dl;
  const float2 a = *reinterpret_cast<const float2*>(ea + (size_t)n * D_ + d);
  const float2 s = *reinterpret_cast<const float2*>(es + (size_t)n * W + dl);
  const float nax = 0.99f * a.x + 0.01f * s.x;
  const float nay = 0.99f * a.y + 0.01f * s.y;
  const float ncs = 0.99f * cs[n] + 0.01f * counts[n];
  const float ntot = *ntot_acc;
  const float sm = (ncs + 1e-5f) / (ntot + N_ * 1e-5f) * ntot;
  float2 oa, ow;
  oa.x = nax; oa.y = nay;
  ow.x = nax / sm; ow.y = nay / sm;
  *reinterpret_cast<float2*>(onea + (size_t)n * D_ + d) = oa;
  *reinterpret_cast<float2*>(oneww + (size_t)n * D_ + d) = ow;
}

// ---------------- scalar outputs (f32) ----------------
__global__ void k_scal_r6(const float* __restrict__ loss_acc, const float* __restrict__ ent_acc,
                          float* __restrict__ operp, float* __restrict__ oloss) {
  if (threadIdx.x == 0) {
    *operp = expf(-*ent_acc);
    *oloss = 0.25f * (*loss_acc) * (1.0f / 2097152.0f);
  }
}

extern "C" void kernel_launch(void* const* d_in, const int* in_sizes, int n_in,
                              void* d_out, int out_size, void* d_ws, size_t ws_size,
                              hipStream_t stream) {
  (void)in_sizes; (void)n_in; (void)out_size;
  const float* z = (const float*)d_in[0];
  const float* weight = (const float*)d_in[1];
  const float* cs = (const float*)d_in[2];
  const float* ea = (const float*)d_in[3];
  float* out = (float*)d_out;  // FLOAT32 outputs (reference dtype)
  char* ws = (char*)d_ws;

  int W = 256;
  while (W > 64 && W_ES + (size_t)N_ * 4 * W > ws_size) W >>= 1;

  float* counts = (float*)(ws + W_CNT);
  float* scal = (float*)(ws + W_SCAL);
  float* z2 = (float*)(ws + W_Z2);
  float* w2 = (float*)(ws + W_W2);
  int* idxi = (int*)(ws + W_IDXI);
  unsigned long long* pack = (unsigned long long*)(ws + W_PACK);
  float* es = (float*)(ws + W_ES);

  hipMemsetAsync(ws + W_CNT, 0, 65792, stream);  // counts + scalars

  hipLaunchKernelGGL(k_z2_r6, dim3(128), dim3(256), 0, stream, z, z2);
  hipLaunchKernelGGL(k_rowsq_r6, dim3(N_ / 4), dim3(256), 0, stream, weight, w2);
  hipLaunchKernelGGL(k_dist_r6, dim3(64, 8), dim3(256), 0, stream, z, weight, z2, w2, pack);
  hipLaunchKernelGGL(k_cand_r6, dim3(BT_ / 4), dim3(256), 0, stream, z, weight, pack,
                     idxi, counts, out + O_IDX, scal + 0);
  hipLaunchKernelGGL(k_gather_r6, dim3(32, 8), dim3(256), 0, stream, weight, idxi, out + O_OUT);
  hipLaunchKernelGGL(k_fincnt_r6, dim3(64), dim3(256), 0, stream, cs, counts, out + O_NCS,
                     scal + 1, scal + 2);

  for (int dbase = 0; dbase < D_; dbase += W) {
    hipMemsetAsync(ws + W_ES, 0, (size_t)N_ * 4 * W, stream);
    hipLaunchKernelGGL(k_scatter_r6, dim3(128), dim3(256), 0, stream, z, idxi, es, dbase, W);
    hipLaunchKernelGGL(k_finw_r6, dim3(N_), dim3(W / 2), 0, stream, ea, es, cs, counts,
                       scal + 2, dbase, W, out + O_NEWW, out + O_NEA);
  }
  hipLaunchKernelGGL(k_scal_r6, dim3(1), dim3(64), 0, stream, scal + 0, scal + 1,
                     out + O_PERP, out + O_LOSS);
}

// Round 7
// 956.844 us; speedup vs baseline: 1.2769x; 1.2769x over previous
//
#include <hip/hip_runtime.h>
#include <hip/hip_bf16.h>

// EMAVectorQuantizer: B=8, D=256, T=1024, BT=8192, N=16384
// Outputs (FLOAT32, concat): out[B,D,T], perplexity, idx[BT], loss,
// new_weight[N,D], new_cluster_size[N], new_embed_avg[N,D] = 10,510,338 f32

#define B_ 8
#define D_ 256
#define T_ 1024
#define BT_ 8192
#define N_ 16384

// d_out element offsets (float32 elements)
#define O_OUT   0
#define O_PERP  2097152
#define O_IDX   2097153
#define O_LOSS  2105345
#define O_NEWW  2105346
#define O_NCS   6299650
#define O_NEA   6316034

// workspace byte offsets (total 2.29 MB; ws_size >= 4.92 MB proven in R4/R5)
#define W_CNT   0ull        // counts[N] f32 (zeroed)
#define W_SCAL  65536ull    // scalars: [0]=loss_sum [1]=ent [2]=ntot (zeroed)
#define W_Z2    65792ull    // z2[BT] f32
#define W_W2    98560ull    // w2[N] f32
#define W_IDXI  164096ull   // idx int32[BT]
#define W_PACK  196864ull   // pack[BT][32] u64 candidates (2 MB, fully overwritten)

typedef __attribute__((ext_vector_type(8))) short short8;
typedef __attribute__((ext_vector_type(4))) float f32x4;

__device__ __forceinline__ short f2bf(float v) {
  __hip_bfloat16 h = __float2bfloat16(v);
  return *reinterpret_cast<short*>(&h);
}
__device__ __forceinline__ float bf2f(short s) {
  __hip_bfloat16 h = *reinterpret_cast<__hip_bfloat16*>(&s);
  return __bfloat162float(h);
}

// ---------------- z2[b*T+t] = sum_d z[b][d][t]^2 ----------------
__global__ void k_z2_r7(const float* __restrict__ z, float* __restrict__ z2) {
  __shared__ float part[4][64];
  const int blk = blockIdx.x;  // b*16 + tchunk
  const int b = blk >> 4, t0 = (blk & 15) << 6;
  const int lane = threadIdx.x & 63, w = threadIdx.x >> 6;
  const float* base = z + (size_t)b * D_ * T_ + t0 + lane;
  float s = 0.f;
  for (int d = w * 64; d < w * 64 + 64; ++d) {
    const float v = base[(size_t)d * T_];
    s = fmaf(v, v, s);
  }
  part[w][lane] = s;
  __syncthreads();
  if (w == 0)
    z2[b * T_ + t0 + lane] = part[0][lane] + part[1][lane] + part[2][lane] + part[3][lane];
}

// ---------------- w2[n] = ||weight[n]||^2 ----------------
__global__ void k_rowsq_r7(const float* __restrict__ m, float* __restrict__ outv) {
  const int row = blockIdx.x * 4 + (threadIdx.x >> 6);
  const int lane = threadIdx.x & 63;
  const float4 v = reinterpret_cast<const float4*>(m + (size_t)row * D_)[lane];
  float s = v.x * v.x + v.y * v.y + v.z * v.z + v.w * v.w;
  for (int o = 32; o; o >>= 1) s += __shfl_xor(s, o);
  if (lane == 0) outv[row] = s;
}

// ------------- split-bf16 MFMA distance + top-2 candidates -------------
// dot = hiz.hiw + hiz.low + loz.hiw  (virtual K = 768, error ~1e-3)
// grid (64 row-blocks of 128, 8 chunks of 2048); 256 thr = 4 waves (2x2).
// Each wave keeps running top-2 per row over its 64-col slice x 16 tiles;
// emits 2 candidates -> 32 candidates/row total, fp64 re-ranked in k_cand.
#define LDA 40  // row stride in bf16 (80 B) - breaks bank conflicts
__global__ __launch_bounds__(256, 2) void k_dist_r7(
    const float* __restrict__ z, const float* __restrict__ weight,
    const float* __restrict__ z2, const float* __restrict__ w2,
    unsigned long long* __restrict__ pack) {
  __shared__ short As[128 * LDA];
  __shared__ short Bs[128 * LDA];

  const int tid = threadIdx.x;
  const int lane = tid & 63, wave = tid >> 6;
  const int quad = lane >> 4, l15 = lane & 15;
  const int rowblk = blockIdx.x, cy = blockIdx.y;
  const int b = rowblk >> 3, t0 = (rowblk & 7) << 7;
  const int r0 = rowblk << 7;
  const int nbase = cy << 11;
  const int wrow = (wave & 1) << 6, wcol = (wave >> 1) << 6;

  // staging mapping: sm = row/col 0..127, kh = k-half 0/1 (16 k-slots each)
  const int sm = tid & 127, kh = tid >> 7;
  const float* zb = z + (size_t)b * D_ * T_ + t0;

  // this lane's 16 row halves of z2
  float z2h[16];
#pragma unroll
  for (int s = 0; s < 16; ++s) {
    const int row = wrow + (s >> 2) * 16 + quad * 4 + (s & 3);
    z2h[s] = 0.5f * z2[r0 + row];
  }

  float rd0[16], rd1[16];
  int ri0[16], ri1[16];
#pragma unroll
  for (int s = 0; s < 16; ++s) { rd0[s] = 3.0e38f; rd1[s] = 3.0e38f; ri0[s] = 0; ri1[s] = 0; }

  for (int ct = 0; ct < 16; ++ct) {
    const int n0 = nbase + (ct << 7);
    float w2h[4];
#pragma unroll
    for (int cf = 0; cf < 4; ++cf) w2h[cf] = 0.5f * w2[n0 + wcol + cf * 16 + l15];

    f32x4 acc[4][4];
#pragma unroll
    for (int i = 0; i < 4; ++i)
#pragma unroll
      for (int j = 0; j < 4; ++j) acc[i][j] = (f32x4)(0.f);

    // virtual K loop: iter 0-7 A=hi B=hi, 8-15 A=hi B=lo, 16-23 A=lo B=hi
    for (int iter = 0; iter < 24; ++iter) {
      const int ai = (iter < 16) ? (iter & 7) : (iter - 16);
      const bool alo = iter >= 16;
      const int bi = (iter < 8) ? iter : ((iter < 16) ? iter - 8 : iter - 16);
      const bool blo = (iter >= 8 && iter < 16);
      __syncthreads();
      // stage A (skip iters 8-15: LDS already holds the same hi slice)
      if (iter < 8 || iter >= 16) {
        short av[16];
#pragma unroll
        for (int j = 0; j < 16; ++j) {
          const float v = zb[(size_t)((ai << 5) + (kh << 4) + j) * T_ + sm];
          const short h = f2bf(v);
          av[j] = alo ? f2bf(v - bf2f(h)) : h;
        }
        *reinterpret_cast<short8*>(&As[sm * LDA + (kh << 4)]) = *reinterpret_cast<short8*>(&av[0]);
        *reinterpret_cast<short8*>(&As[sm * LDA + (kh << 4) + 8]) = *reinterpret_cast<short8*>(&av[8]);
      }
      {
        const float* wp = weight + (size_t)(n0 + sm) * D_ + (bi << 5) + (kh << 4);
        short bv[16];
#pragma unroll
        for (int c = 0; c < 4; ++c) {
          const float4 v = reinterpret_cast<const float4*>(wp)[c];
          const short hx = f2bf(v.x), hy = f2bf(v.y), hz = f2bf(v.z), hw = f2bf(v.w);
          if (blo) {
            bv[c * 4 + 0] = f2bf(v.x - bf2f(hx));
            bv[c * 4 + 1] = f2bf(v.y - bf2f(hy));
            bv[c * 4 + 2] = f2bf(v.z - bf2f(hz));
            bv[c * 4 + 3] = f2bf(v.w - bf2f(hw));
          } else {
            bv[c * 4 + 0] = hx; bv[c * 4 + 1] = hy; bv[c * 4 + 2] = hz; bv[c * 4 + 3] = hw;
          }
        }
        *reinterpret_cast<short8*>(&Bs[sm * LDA + (kh << 4)]) = *reinterpret_cast<short8*>(&bv[0]);
        *reinterpret_cast<short8*>(&Bs[sm * LDA + (kh << 4) + 8]) = *reinterpret_cast<short8*>(&bv[8]);
      }
      __syncthreads();
      short8 af[4], bf[4];
#pragma unroll
      for (int rf = 0; rf < 4; ++rf)
        af[rf] = *reinterpret_cast<const short8*>(&As[(wrow + rf * 16 + l15) * LDA + quad * 8]);
#pragma unroll
      for (int cf = 0; cf < 4; ++cf)
        bf[cf] = *reinterpret_cast<const short8*>(&Bs[(wcol + cf * 16 + l15) * LDA + quad * 8]);
#pragma unroll
      for (int rf = 0; rf < 4; ++rf)
#pragma unroll
        for (int cf = 0; cf < 4; ++cf)
          acc[rf][cf] = __builtin_amdgcn_mfma_f32_16x16x32_bf16(af[rf], bf[cf], acc[rf][cf], 0, 0, 0);
    }

    // epilogue: halved distance d/2 = z2/2 + w2/2 - dot; running top-2
#pragma unroll
    for (int rf = 0; rf < 4; ++rf)
#pragma unroll
      for (int cf = 0; cf < 4; ++cf)
#pragma unroll
        for (int reg = 0; reg < 4; ++reg) {
          const int s = rf * 4 + reg;
          const float d = z2h[s] + w2h[cf] - acc[rf][cf][reg];
          const int idx = n0 + wcol + cf * 16 + l15;
          if (d < rd1[s]) {
            if (d < rd0[s]) { rd1[s] = rd0[s]; ri1[s] = ri0[s]; rd0[s] = d; ri0[s] = idx; }
            else { rd1[s] = d; ri1[s] = idx; }
          }
        }
  }

  // merge top-2 across the 16 lanes (cols) of each row via packed-u64 butterfly
#pragma unroll
  for (int s = 0; s < 16; ++s) {
    unsigned long long p0 = ((unsigned long long)__float_as_uint(rd0[s]) << 32) | (unsigned int)ri0[s];
    unsigned long long p1 = ((unsigned long long)__float_as_uint(rd1[s]) << 32) | (unsigned int)ri1[s];
    for (int off = 1; off < 16; off <<= 1) {
      const unsigned long long q0 = __shfl_xor(p0, off);
      const unsigned long long q1 = __shfl_xor(p1, off);
      const unsigned long long lo = p0 < q0 ? p0 : q0;
      const unsigned long long mx = p0 < q0 ? q0 : p0;
      const unsigned long long mn1 = p1 < q1 ? p1 : q1;
      p0 = lo;
      p1 = mx < mn1 ? mx : mn1;
    }
    if (l15 == 0) {
      const int row = wrow + (s >> 2) * 16 + quad * 4 + (s & 3);
      unsigned long long* dst = pack + (size_t)(r0 + row) * 32 + cy * 4 + (wave >> 1) * 2;
      dst[0] = p0;
      dst[1] = p1;
    }
  }
}

// ---- fp64 re-rank of 32 candidates; idx + counts + loss ----
__global__ void k_cand_r7(const float* __restrict__ z, const float* __restrict__ weight,
                          const unsigned long long* __restrict__ pack,
                          int* __restrict__ idxi, float* __restrict__ counts,
                          float* __restrict__ oidx, float* __restrict__ loss_acc) {
  const int row = blockIdx.x * 4 + (threadIdx.x >> 6);
  const int lane = threadIdx.x & 63;
  const int b = row >> 10, t = row & 1023;
  float zc[4];
#pragma unroll
  for (int c = 0; c < 4; ++c)
    zc[c] = z[((size_t)b * D_ + (lane << 2) + c) * T_ + t];
  double best = 1.0e300;
  int bestid = 0;
  for (int c = 0; c < 32; ++c) {
    const int cand = (int)(pack[(size_t)row * 32 + c] & 0xFFFFFFFFull) & 16383;
    const float4 wv = reinterpret_cast<const float4*>(weight + (size_t)cand * D_)[lane];
    const double d0 = (double)zc[0] - (double)wv.x;
    const double d1 = (double)zc[1] - (double)wv.y;
    const double d2 = (double)zc[2] - (double)wv.z;
    const double d3 = (double)zc[3] - (double)wv.w;
    double s = d0 * d0 + d1 * d1 + d2 * d2 + d3 * d3;
    for (int o = 32; o; o >>= 1) s += __shfl_xor(s, o);
    if (s < best || (s == best && cand < bestid)) { best = s; bestid = cand; }
  }
  if (lane == 0) {
    idxi[row] = bestid;
    oidx[row] = (float)bestid;
    atomicAdd(&counts[bestid], 1.0f);
    atomicAdd(loss_acc, (float)best);
  }
}

// ---------------- gather codebook rows -> out[B,D,T] (f32) ----------------
__global__ void k_gather_r7(const float* __restrict__ weight, const int* __restrict__ idxi,
                            float* __restrict__ oout) {
  __shared__ float tile[32][257];
  __shared__ int ids[32];
  const int b = blockIdx.y, t0 = blockIdx.x << 5;
  const int lane = threadIdx.x & 63, wave = threadIdx.x >> 6;
  if (threadIdx.x < 32) ids[threadIdx.x] = idxi[b * T_ + t0 + threadIdx.x] & 16383;
  __syncthreads();
  for (int i = 0; i < 8; ++i) {
    const int tl = (wave << 3) + i;
    const float4 v = reinterpret_cast<const float4*>(weight + (size_t)ids[tl] * D_)[lane];
    tile[tl][(lane << 2) + 0] = v.x;
    tile[tl][(lane << 2) + 1] = v.y;
    tile[tl][(lane << 2) + 2] = v.z;
    tile[tl][(lane << 2) + 3] = v.w;
  }
  __syncthreads();
  const int tp = threadIdx.x & 31, dg = threadIdx.x >> 5;
  for (int it = 0; it < 32; ++it) {
    const int d = (dg << 5) + it;
    oout[((size_t)b * D_ + d) * T_ + t0 + tp] = tile[tp][d];
  }
}

// ---------------- new_embed_avg init: 0.99*ea -> out[O_NEA] ----------------
__global__ void k_neainit_r7(const float* __restrict__ ea, float* __restrict__ onea) {
  const int i = blockIdx.x * 256 + threadIdx.x;
  onea[i] = 0.99f * ea[i];
}

// ---- scatter 0.01*z directly into out[O_NEA] (LDS transpose, coalesced) ----
__global__ void k_scatter_r7(const float* __restrict__ z, const int* __restrict__ idxi,
                             float* __restrict__ onea) {
  __shared__ float lds[64][65];
  __shared__ int ids[64];
  const int blk = blockIdx.x;
  const int b = blk >> 4, t0 = (blk & 15) << 6;
  const int lane = threadIdx.x & 63, w = threadIdx.x >> 6;
  if (threadIdx.x < 64) ids[threadIdx.x] = idxi[b * T_ + t0 + threadIdx.x] & 16383;
  for (int dc = 0; dc < D_; dc += 64) {
    __syncthreads();
    for (int i = 0; i < 16; ++i) {
      const int dd = (w << 4) + i;
      lds[dd][lane] = z[((size_t)b * D_ + dc + dd) * T_ + t0 + lane];
    }
    __syncthreads();
    for (int i = 0; i < 16; ++i) {
      const int tl = (w << 4) + i;
      atomicAdd(&onea[(size_t)ids[tl] * D_ + dc + lane], 0.01f * lds[lane][tl]);
    }
  }
}

// ---------------- new_cluster_size + entropy + ntot ----------------
__global__ void k_fincnt_r7(const float* __restrict__ cs, const float* __restrict__ counts,
                            float* __restrict__ oncs, float* __restrict__ ent_acc,
                            float* __restrict__ ntot_acc) {
  __shared__ float red[8];
  const int n = blockIdx.x * 256 + threadIdx.x;
  const float c = counts[n];
  const float ncs = 0.99f * cs[n] + 0.01f * c;
  oncs[n] = ncs;
  const float p = c * (1.0f / 8192.0f);
  float se = p * logf(p + 1e-10f);
  float sn = ncs;
  for (int o = 32; o; o >>= 1) {
    se += __shfl_xor(se, o);
    sn += __shfl_xor(sn, o);
  }
  const int lane = threadIdx.x & 63, wave = threadIdx.x >> 6;
  if (lane == 0) { red[wave] = se; red[4 + wave] = sn; }
  __syncthreads();
  if (threadIdx.x == 0) {
    atomicAdd(ent_acc, red[0] + red[1] + red[2] + red[3]);
    atomicAdd(ntot_acc, red[4] + red[5] + red[6] + red[7]);
  }
}

// ---------------- new_weight = new_embed_avg / smoothed ----------------
__global__ void k_finw_r7(const float* __restrict__ cs, const float* __restrict__ counts,
                          const float* __restrict__ ntot_acc,
                          const float* __restrict__ onea, float* __restrict__ oneww) {
  const int n = blockIdx.x;
  const int dl = threadIdx.x << 1;
  const float2 a = *reinterpret_cast<const float2*>(onea + (size_t)n * D_ + dl);
  const float ncs = 0.99f * cs[n] + 0.01f * counts[n];
  const float ntot = *ntot_acc;
  const float sm = (ncs + 1e-5f) / (ntot + N_ * 1e-5f) * ntot;
  float2 ow;
  ow.x = a.x / sm;
  ow.y = a.y / sm;
  *reinterpret_cast<float2*>(oneww + (size_t)n * D_ + dl) = ow;
}

// ---------------- scalar outputs ----------------
__global__ void k_scal_r7(const float* __restrict__ loss_acc, const float* __restrict__ ent_acc,
                          float* __restrict__ operp, float* __restrict__ oloss) {
  if (threadIdx.x == 0) {
    *operp = expf(-*ent_acc);
    *oloss = 0.25f * (*loss_acc) * (1.0f / 2097152.0f);
  }
}

extern "C" void kernel_launch(void* const* d_in, const int* in_sizes, int n_in,
                              void* d_out, int out_size, void* d_ws, size_t ws_size,
                              hipStream_t stream) {
  (void)in_sizes; (void)n_in; (void)out_size; (void)ws_size;
  const float* z = (const float*)d_in[0];
  const float* weight = (const float*)d_in[1];
  const float* cs = (const float*)d_in[2];
  const float* ea = (const float*)d_in[3];
  float* out = (float*)d_out;
  char* ws = (char*)d_ws;

  float* counts = (float*)(ws + W_CNT);
  float* scal = (float*)(ws + W_SCAL);
  float* z2 = (float*)(ws + W_Z2);
  float* w2 = (float*)(ws + W_W2);
  int* idxi = (int*)(ws + W_IDXI);
  unsigned long long* pack = (unsigned long long*)(ws + W_PACK);

  hipMemsetAsync(ws + W_CNT, 0, 65792, stream);  // counts + scalars

  hipLaunchKernelGGL(k_z2_r7, dim3(128), dim3(256), 0, stream, z, z2);
  hipLaunchKernelGGL(k_rowsq_r7, dim3(N_ / 4), dim3(256), 0, stream, weight, w2);
  hipLaunchKernelGGL(k_dist_r7, dim3(64, 8), dim3(256), 0, stream, z, weight, z2, w2, pack);
  hipLaunchKernelGGL(k_cand_r7, dim3(BT_ / 4), dim3(256), 0, stream, z, weight, pack,
                     idxi, counts, out + O_IDX, scal + 0);
  hipLaunchKernelGGL(k_gather_r7, dim3(32, 8), dim3(256), 0, stream, weight, idxi, out + O_OUT);
  hipLaunchKernelGGL(k_fincnt_r7, dim3(64), dim3(256), 0, stream, cs, counts, out + O_NCS,
                     scal + 1, scal + 2);
  hipLaunchKernelGGL(k_neainit_r7, dim3(N_ * D_ / 256), dim3(256), 0, stream, ea, out + O_NEA);
  hipLaunchKernelGGL(k_scatter_r7, dim3(128), dim3(256), 0, stream, z, idxi, out + O_NEA);
  hipLaunchKernelGGL(k_finw_r7, dim3(N_), dim3(128), 0, stream, cs, counts, scal + 2,
                     out + O_NEA, out + O_NEWW);
  hipLaunchKernelGGL(k_scal_r7, dim3(1), dim3(64), 0, stream, scal + 0, scal + 1,
                     out + O_PERP, out + O_LOSS);
}

// Round 8
// 520.045 us; speedup vs baseline: 2.3494x; 1.8399x over previous
//
#include <hip/hip_runtime.h>
#include <hip/hip_bf16.h>

// EMAVectorQuantizer: B=8, D=256, T=1024, BT=8192, N=16384
// Outputs (FLOAT32, concat): out[B,D,T], perplexity, idx[BT], loss,
// new_weight[N,D], new_cluster_size[N], new_embed_avg[N,D] = 10,510,338 f32

#define B_ 8
#define D_ 256
#define T_ 1024
#define BT_ 8192
#define N_ 16384

// d_out element offsets (float32 elements)
#define O_OUT   0
#define O_PERP  2097152
#define O_IDX   2097153
#define O_LOSS  2105345
#define O_NEWW  2105346
#define O_NCS   6299650
#define O_NEA   6316034

// workspace byte offsets (13.2 MB total; R1-vs-R5 bit-identical outputs imply ws>=25MB)
#define W_CNT   0ull        // counts[N] f32 (zeroed)
#define W_SCAL  65536ull    // scalars: [0]=loss_sum [1]=ent [2]=ntot (zeroed)
#define W_Z2    65792ull    // z2[BT] f32 (zeroed; accumulated via atomics)
#define W_W2    98560ull    // w2[N] f32
#define W_IDXI  164096ull   // idx int32[BT]
#define W_PACK  196864ull   // pack[BT][16] u64 candidates (1 MB, fully written)
#define W_ZH    1245440ull  // zh[BT][D] fp16, transposed z (4 MB)
#define W_WH    5439744ull  // wh[N][D] fp16 (8 MB)

typedef __attribute__((ext_vector_type(8))) _Float16 half8;
typedef __attribute__((ext_vector_type(4))) _Float16 half4;
typedef __attribute__((ext_vector_type(4))) float f32x4;

__device__ __forceinline__ void gl_lds(const void* g, void* l) {
  __builtin_amdgcn_global_load_lds(
      (const __attribute__((address_space(1))) unsigned int*)g,
      (__attribute__((address_space(3))) unsigned int*)l, 16, 0, 0);
}

// ---- prep z: transpose to zh[BT][D] fp16 + z2 partial sums ----
__global__ void k_prepz_r8(const float* __restrict__ z, _Float16* __restrict__ zh,
                           float* __restrict__ z2) {
  __shared__ float tile[64][65];
  const int t0 = blockIdx.x << 6, d0 = blockIdx.y << 6, b = blockIdx.z;
  const int tt = threadIdx.x & 63, q = threadIdx.x >> 6;
  float s = 0.f;
  for (int i = 0; i < 16; ++i) {
    const int dd = q + (i << 2);
    const float v = z[((size_t)b * D_ + d0 + dd) * T_ + t0 + tt];
    tile[tt][dd] = v;
    s = fmaf(v, v, s);
  }
  atomicAdd(&z2[b * T_ + t0 + tt], s);
  __syncthreads();
  for (int i = 0; i < 16; ++i) {
    const int ttw = q + (i << 2);
    zh[((size_t)(b * T_ + t0 + ttw)) * D_ + d0 + tt] = (_Float16)tile[ttw][tt];
  }
}

// ---- prep w: wh[N][D] fp16 + w2 (wave per row) ----
__global__ void k_prepw_r8(const float* __restrict__ w, _Float16* __restrict__ wh,
                           float* __restrict__ w2) {
  const int row = blockIdx.x * 4 + (threadIdx.x >> 6);
  const int lane = threadIdx.x & 63;
  const float4 v = reinterpret_cast<const float4*>(w + (size_t)row * D_)[lane];
  half4 h;
  h[0] = (_Float16)v.x; h[1] = (_Float16)v.y; h[2] = (_Float16)v.z; h[3] = (_Float16)v.w;
  *reinterpret_cast<half4*>(wh + (size_t)row * D_ + (lane << 2)) = h;
  float s = v.x * v.x + v.y * v.y + v.z * v.z + v.w * v.w;
  for (int o = 32; o; o >>= 1) s += __shfl_xor(s, o);
  if (lane == 0) w2[row] = s;
}

// ---- fp16 MFMA distance GEMM + top-2 per (row, 2048-col slice) ----
// grid (64 rowblocks of 128, 8 cy); 256 thr = 4 waves (2 row x 2 col).
// LDS XOR-swizzle: slot s holds chunk k8g = (s&7)^(m&7), DMA-compatible.
__global__ __launch_bounds__(256, 2) void k_dist_r8(
    const _Float16* __restrict__ zh, const _Float16* __restrict__ wh,
    const float* __restrict__ z2, const float* __restrict__ w2,
    unsigned long long* __restrict__ pack) {
  __shared__ _Float16 As[8192];  // 128 rows x 64 k (16 KB)
  __shared__ _Float16 Bs[8192];
  __shared__ unsigned long long Ms[2][128][2];  // cross-wave merge (4 KB)

  const int tid = threadIdx.x;
  const int lane = tid & 63, wave = tid >> 6;
  const int quad = lane >> 4, l15 = lane & 15;
  const int r0 = blockIdx.x << 7;
  const int cy = blockIdx.y;
  const int nbase = cy << 11;
  const int wrow = (wave & 1) << 6, wcol = (wave >> 1) << 6;

  // staging geometry: call j stages slots (wave*4+j)*64 + lane
  int sm[4], sc[4];
#pragma unroll
  for (int j = 0; j < 4; ++j) {
    const int slot = (wave * 4 + j) * 64 + lane;
    sm[j] = slot >> 3;
    sc[j] = (slot & 7) ^ (sm[j] & 7);  // global k8 chunk landing in this slot
  }

  float z2h[16];
#pragma unroll
  for (int s = 0; s < 16; ++s)
    z2h[s] = 0.5f * z2[r0 + wrow + (s >> 2) * 16 + quad * 4 + (s & 3)];

  float rd0[16], rd1[16];
  int ri0[16], ri1[16];
#pragma unroll
  for (int s = 0; s < 16; ++s) { rd0[s] = 3.0e38f; rd1[s] = 3.0e38f; ri0[s] = 0; ri1[s] = 0; }

  for (int ct = 0; ct < 16; ++ct) {
    const int n0 = nbase + (ct << 7);
    float w2h[4];
#pragma unroll
    for (int cf = 0; cf < 4; ++cf) w2h[cf] = 0.5f * w2[n0 + wcol + cf * 16 + l15];

    f32x4 acc[4][4];
#pragma unroll
    for (int i = 0; i < 4; ++i)
#pragma unroll
      for (int j = 0; j < 4; ++j) acc[i][j] = (f32x4)(0.f);

    for (int kc = 0; kc < 4; ++kc) {  // BK=64
      __syncthreads();
#pragma unroll
      for (int j = 0; j < 4; ++j)
        gl_lds(zh + ((size_t)(r0 + sm[j]) << 8) + (kc << 6) + (sc[j] << 3),
               As + (wave * 4 + j) * 512);
#pragma unroll
      for (int j = 0; j < 4; ++j)
        gl_lds(wh + ((size_t)(n0 + sm[j]) << 8) + (kc << 6) + (sc[j] << 3),
               Bs + (wave * 4 + j) * 512);
      __syncthreads();
#pragma unroll
      for (int kl = 0; kl < 2; ++kl) {  // 2 x K=32
        const int k8 = (kl << 2) + quad;
        half8 af[4], bf[4];
#pragma unroll
        for (int rf = 0; rf < 4; ++rf) {
          const int m = wrow + rf * 16 + l15;
          af[rf] = *reinterpret_cast<const half8*>(&As[(m << 6) + ((k8 ^ (m & 7)) << 3)]);
        }
#pragma unroll
        for (int cf = 0; cf < 4; ++cf) {
          const int n = wcol + cf * 16 + l15;
          bf[cf] = *reinterpret_cast<const half8*>(&Bs[(n << 6) + ((k8 ^ (n & 7)) << 3)]);
        }
#pragma unroll
        for (int rf = 0; rf < 4; ++rf)
#pragma unroll
          for (int cf = 0; cf < 4; ++cf)
            acc[rf][cf] = __builtin_amdgcn_mfma_f32_16x16x32_f16(af[rf], bf[cf], acc[rf][cf], 0, 0, 0);
      }
    }
    // d/2 = z2/2 + w2/2 - dot ; running top-2 per row-slot
#pragma unroll
    for (int rf = 0; rf < 4; ++rf)
#pragma unroll
      for (int cf = 0; cf < 4; ++cf) {
        const int idx = n0 + wcol + cf * 16 + l15;
#pragma unroll
        for (int reg = 0; reg < 4; ++reg) {
          const int s = rf * 4 + reg;
          const float d = z2h[s] + w2h[cf] - acc[rf][cf][reg];
          if (d < rd1[s]) {
            if (d < rd0[s]) { rd1[s] = rd0[s]; ri1[s] = ri0[s]; rd0[s] = d; ri0[s] = idx; }
            else { rd1[s] = d; ri1[s] = idx; }
          }
        }
      }
  }

  // merge top-2 across the 16 col-lanes of each quad (xor stays within quad)
#pragma unroll
  for (int s = 0; s < 16; ++s) {
    unsigned long long p0 = ((unsigned long long)__float_as_uint(rd0[s]) << 32) | (unsigned int)ri0[s];
    unsigned long long p1 = ((unsigned long long)__float_as_uint(rd1[s]) << 32) | (unsigned int)ri1[s];
    for (int off = 1; off < 16; off <<= 1) {
      const unsigned long long q0 = __shfl_xor(p0, off);
      const unsigned long long q1 = __shfl_xor(p1, off);
      const unsigned long long lo = p0 < q0 ? p0 : q0;
      const unsigned long long mx = p0 < q0 ? q0 : p0;
      const unsigned long long mn1 = p1 < q1 ? p1 : q1;
      p0 = lo;
      p1 = mx < mn1 ? mx : mn1;
    }
    if (l15 == 0) {
      const int row = wrow + (s >> 2) * 16 + quad * 4 + (s & 3);
      Ms[wave >> 1][row][0] = p0;
      Ms[wave >> 1][row][1] = p1;
    }
  }
  __syncthreads();
  // merge the two col-slices -> top-2 per (row, cy)
  if (tid < 128) {
    const unsigned long long a0 = Ms[0][tid][0], a1 = Ms[0][tid][1];
    const unsigned long long b0 = Ms[1][tid][0], b1 = Ms[1][tid][1];
    const unsigned long long p0 = a0 < b0 ? a0 : b0;
    const unsigned long long p1 = a0 < b0 ? (a1 < b0 ? a1 : b0) : (b1 < a0 ? b1 : a0);
    unsigned long long* dst = pack + (((size_t)(r0 + tid)) << 4) + (cy << 1);
    dst[0] = p0;
    dst[1] = p1;
  }
}

// ---- fp64 re-rank of 16 candidates; idx + counts + loss ----
__global__ void k_cand_r8(const float* __restrict__ z, const float* __restrict__ weight,
                          const unsigned long long* __restrict__ pack,
                          int* __restrict__ idxi, float* __restrict__ counts,
                          float* __restrict__ oidx, float* __restrict__ loss_acc) {
  const int row = blockIdx.x * 4 + (threadIdx.x >> 6);
  const int lane = threadIdx.x & 63;
  const int b = row >> 10, t = row & 1023;
  float zc[4];
#pragma unroll
  for (int c = 0; c < 4; ++c)
    zc[c] = z[((size_t)b * D_ + (lane << 2) + c) * T_ + t];
  double best = 1.0e300;
  int bestid = 0;
  for (int c = 0; c < 16; ++c) {
    const int cand = (int)(pack[((size_t)row << 4) + c] & 0xFFFFFFFFull) & 16383;
    const float4 wv = reinterpret_cast<const float4*>(weight + (size_t)cand * D_)[lane];
    const double d0 = (double)zc[0] - (double)wv.x;
    const double d1 = (double)zc[1] - (double)wv.y;
    const double d2 = (double)zc[2] - (double)wv.z;
    const double d3 = (double)zc[3] - (double)wv.w;
    double s = d0 * d0 + d1 * d1 + d2 * d2 + d3 * d3;
    for (int o = 32; o; o >>= 1) s += __shfl_xor(s, o);
    if (s < best || (s == best && cand < bestid)) { best = s; bestid = cand; }
  }
  if (lane == 0) {
    idxi[row] = bestid;
    oidx[row] = (float)bestid;
    atomicAdd(&counts[bestid], 1.0f);
    atomicAdd(loss_acc, (float)best);
  }
}

// ---------------- gather codebook rows -> out[B,D,T] (f32) ----------------
__global__ void k_gather_r8(const float* __restrict__ weight, const int* __restrict__ idxi,
                            float* __restrict__ oout) {
  __shared__ float tile[32][257];
  __shared__ int ids[32];
  const int b = blockIdx.y, t0 = blockIdx.x << 5;
  const int lane = threadIdx.x & 63, wave = threadIdx.x >> 6;
  if (threadIdx.x < 32) ids[threadIdx.x] = idxi[b * T_ + t0 + threadIdx.x] & 16383;
  __syncthreads();
  for (int i = 0; i < 8; ++i) {
    const int tl = (wave << 3) + i;
    const float4 v = reinterpret_cast<const float4*>(weight + (size_t)ids[tl] * D_)[lane];
    tile[tl][(lane << 2) + 0] = v.x;
    tile[tl][(lane << 2) + 1] = v.y;
    tile[tl][(lane << 2) + 2] = v.z;
    tile[tl][(lane << 2) + 3] = v.w;
  }
  __syncthreads();
  const int tp = threadIdx.x & 31, dg = threadIdx.x >> 5;
  for (int it = 0; it < 32; ++it) {
    const int d = (dg << 5) + it;
    oout[((size_t)b * D_ + d) * T_ + t0 + tp] = tile[tp][d];
  }
}

// ---------------- new_embed_avg init: 0.99*ea -> out[O_NEA] ----------------
__global__ void k_neainit_r8(const float* __restrict__ ea, float* __restrict__ onea) {
  const int i = blockIdx.x * 256 + threadIdx.x;
  onea[i] = 0.99f * ea[i];
}

// ---- scatter 0.01*z into out[O_NEA] (LDS transpose, coalesced atomics) ----
__global__ void k_scatter_r8(const float* __restrict__ z, const int* __restrict__ idxi,
                             float* __restrict__ onea) {
  __shared__ float lds[64][65];
  __shared__ int ids[64];
  const int blk = blockIdx.x;
  const int b = blk >> 4, t0 = (blk & 15) << 6;
  const int lane = threadIdx.x & 63, w = threadIdx.x >> 6;
  if (threadIdx.x < 64) ids[threadIdx.x] = idxi[b * T_ + t0 + threadIdx.x] & 16383;
  for (int dc = 0; dc < D_; dc += 64) {
    __syncthreads();
    for (int i = 0; i < 16; ++i) {
      const int dd = (w << 4) + i;
      lds[dd][lane] = z[((size_t)b * D_ + dc + dd) * T_ + t0 + lane];
    }
    __syncthreads();
    for (int i = 0; i < 16; ++i) {
      const int tl = (w << 4) + i;
      atomicAdd(&onea[(size_t)ids[tl] * D_ + dc + lane], 0.01f * lds[lane][tl]);
    }
  }
}

// ---------------- new_cluster_size + entropy + ntot ----------------
__global__ void k_fincnt_r8(const float* __restrict__ cs, const float* __restrict__ counts,
                            float* __restrict__ oncs, float* __restrict__ ent_acc,
                            float* __restrict__ ntot_acc) {
  __shared__ float red[8];
  const int n = blockIdx.x * 256 + threadIdx.x;
  const float c = counts[n];
  const float ncs = 0.99f * cs[n] + 0.01f * c;
  oncs[n] = ncs;
  const float p = c * (1.0f / 8192.0f);
  float se = p * logf(p + 1e-10f);
  float sn = ncs;
  for (int o = 32; o; o >>= 1) {
    se += __shfl_xor(se, o);
    sn += __shfl_xor(sn, o);
  }
  const int lane = threadIdx.x & 63, wave = threadIdx.x >> 6;
  if (lane == 0) { red[wave] = se; red[4 + wave] = sn; }
  __syncthreads();
  if (threadIdx.x == 0) {
    atomicAdd(ent_acc, red[0] + red[1] + red[2] + red[3]);
    atomicAdd(ntot_acc, red[4] + red[5] + red[6] + red[7]);
  }
}

// ---------------- new_weight = new_embed_avg / smoothed ----------------
__global__ void k_finw_r8(const float* __restrict__ cs, const float* __restrict__ counts,
                          const float* __restrict__ ntot_acc,
                          const float* __restrict__ onea, float* __restrict__ oneww) {
  const int n = blockIdx.x;
  const int dl = threadIdx.x << 1;
  const float2 a = *reinterpret_cast<const float2*>(onea + (size_t)n * D_ + dl);
  const float ncs = 0.99f * cs[n] + 0.01f * counts[n];
  const float ntot = *ntot_acc;
  const float sm = (ncs + 1e-5f) / (ntot + N_ * 1e-5f) * ntot;
  float2 ow;
  ow.x = a.x / sm;
  ow.y = a.y / sm;
  *reinterpret_cast<float2*>(oneww + (size_t)n * D_ + dl) = ow;
}

// ---------------- scalar outputs ----------------
__global__ void k_scal_r8(const float* __restrict__ loss_acc, const float* __restrict__ ent_acc,
                          float* __restrict__ operp, float* __restrict__ oloss) {
  if (threadIdx.x == 0) {
    *operp = expf(-*ent_acc);
    *oloss = 0.25f * (*loss_acc) * (1.0f / 2097152.0f);
  }
}

extern "C" void kernel_launch(void* const* d_in, const int* in_sizes, int n_in,
                              void* d_out, int out_size, void* d_ws, size_t ws_size,
                              hipStream_t stream) {
  (void)in_sizes; (void)n_in; (void)out_size; (void)ws_size;
  const float* z = (const float*)d_in[0];
  const float* weight = (const float*)d_in[1];
  const float* cs = (const float*)d_in[2];
  const float* ea = (const float*)d_in[3];
  float* out = (float*)d_out;
  char* ws = (char*)d_ws;

  float* counts = (float*)(ws + W_CNT);
  float* scal = (float*)(ws + W_SCAL);
  float* z2 = (float*)(ws + W_Z2);
  float* w2 = (float*)(ws + W_W2);
  int* idxi = (int*)(ws + W_IDXI);
  unsigned long long* pack = (unsigned long long*)(ws + W_PACK);
  _Float16* zh = (_Float16*)(ws + W_ZH);
  _Float16* wh = (_Float16*)(ws + W_WH);

  hipMemsetAsync(ws + W_CNT, 0, 98560, stream);  // counts + scalars + z2

  hipLaunchKernelGGL(k_prepz_r8, dim3(16, 4, 8), dim3(256), 0, stream, z, zh, z2);
  hipLaunchKernelGGL(k_prepw_r8, dim3(N_ / 4), dim3(256), 0, stream, weight, wh, w2);
  hipLaunchKernelGGL(k_dist_r8, dim3(64, 8), dim3(256), 0, stream, zh, wh, z2, w2, pack);
  hipLaunchKernelGGL(k_cand_r8, dim3(BT_ / 4), dim3(256), 0, stream, z, weight, pack,
                     idxi, counts, out + O_IDX, scal + 0);
  hipLaunchKernelGGL(k_gather_r8, dim3(32, 8), dim3(256), 0, stream, weight, idxi, out + O_OUT);
  hipLaunchKernelGGL(k_fincnt_r8, dim3(64), dim3(256), 0, stream, cs, counts, out + O_NCS,
                     scal + 1, scal + 2);
  hipLaunchKernelGGL(k_neainit_r8, dim3(N_ * D_ / 256), dim3(256), 0, stream, ea, out + O_NEA);
  hipLaunchKernelGGL(k_scatter_r8, dim3(128), dim3(256), 0, stream, z, idxi, out + O_NEA);
  hipLaunchKernelGGL(k_finw_r8, dim3(N_), dim3(128), 0, stream, cs, counts, scal + 2,
                     out + O_NEA, out + O_NEWW);
  hipLaunchKernelGGL(k_scal_r8, dim3(1), dim3(64), 0, stream, scal + 0, scal + 1,
                     out + O_PERP, out + O_LOSS);
}